// Round 1
// baseline (1556.015 us; speedup 1.0000x reference)
//
#include <hip/hip_runtime.h>
#include <hip/hip_bf16.h>

#define NN 2000
#define BB 32
#define FF 32
#define LL 10

// ---------------------------------------------------------------------------
// K1/K3: out(rows,32) = x(rows,32) @ w(32,32)   (no activation)
// ---------------------------------------------------------------------------
__global__ void small_mm(const float* __restrict__ x, const float* __restrict__ w,
                         float* __restrict__ out, int rows) {
    int t = blockIdx.x * blockDim.x + threadIdx.x;
    if (t >= rows * 32) return;
    int f = t & 31;
    int r = t >> 5;
    const float* xr = x + (size_t)r * 32;
    float acc = 0.f;
#pragma unroll
    for (int k = 0; k < 32; ++k) acc += xr[k] * w[k * 32 + f];
    out[t] = acc;
}

// ---------------------------------------------------------------------------
// K2/K4: y[b][i][f] = relu( sum_j adj[b][i][j] * h[b][j][f] )
// One thread per output row i. adj row streamed as float4 (lane-private,
// contiguous). h row (128 B) is wave-uniform per j -> scalar loads + SGPR-
// operand v_fmac. SUM_ONLY fuses the feature-sum pool (layer 2).
// ---------------------------------------------------------------------------
template <bool SUM_ONLY>
__global__ void gcn_layer(const float* __restrict__ adj, const float* __restrict__ h,
                          float* __restrict__ out, float* __restrict__ rowsum) {
    const int b = blockIdx.y;
    const int i0 = blockIdx.x * blockDim.x + threadIdx.x;
    const int i = (i0 < NN) ? i0 : (NN - 1);   // clamp; masked at store

    const float* __restrict__ arow = adj + ((size_t)b * NN + i) * NN;
    const float* __restrict__ hb   = h + (size_t)b * NN * FF;

    float acc[FF];
#pragma unroll
    for (int f = 0; f < FF; ++f) acc[f] = 0.f;

    for (int j = 0; j < NN; j += 4) {
        const float4 a = *reinterpret_cast<const float4*>(arow + j);
        const float* __restrict__ h0 = hb + (size_t)j * FF;
#pragma unroll
        for (int f = 0; f < FF; ++f) acc[f] += a.x * h0[f];
#pragma unroll
        for (int f = 0; f < FF; ++f) acc[f] += a.y * h0[FF + f];
#pragma unroll
        for (int f = 0; f < FF; ++f) acc[f] += a.z * h0[2 * FF + f];
#pragma unroll
        for (int f = 0; f < FF; ++f) acc[f] += a.w * h0[3 * FF + f];
    }

    if (i0 >= NN) return;

    if (SUM_ONLY) {
        float s = 0.f;
#pragma unroll
        for (int f = 0; f < FF; ++f) s += fmaxf(acc[f], 0.f);
        rowsum[(size_t)b * NN + i] = s;
    } else {
        float* __restrict__ orow = out + ((size_t)b * NN + i) * FF;
#pragma unroll
        for (int f = 0; f < FF; ++f) orow[f] = fmaxf(acc[f], 0.f);
    }
}

// ---------------------------------------------------------------------------
// K5: out[b][l] = sum_i s[b][i] * out_w[l][i] + out_b[l]
// one block per (l, b)
// ---------------------------------------------------------------------------
__global__ void final_linear(const float* __restrict__ s, const float* __restrict__ ow,
                             const float* __restrict__ ob, float* __restrict__ out) {
    const int l = blockIdx.x;
    const int b = blockIdx.y;
    const float* __restrict__ sr = s + (size_t)b * NN;
    const float* __restrict__ wr = ow + (size_t)l * NN;

    float acc = 0.f;
    for (int i = threadIdx.x; i < NN; i += 256) acc += sr[i] * wr[i];

#pragma unroll
    for (int off = 32; off > 0; off >>= 1) acc += __shfl_down(acc, off);

    __shared__ float red[4];
    if ((threadIdx.x & 63) == 0) red[threadIdx.x >> 6] = acc;
    __syncthreads();
    if (threadIdx.x == 0) {
        out[b * LL + l] = red[0] + red[1] + red[2] + red[3] + ob[l];
    }
}

// ---------------------------------------------------------------------------
extern "C" void kernel_launch(void* const* d_in, const int* in_sizes, int n_in,
                              void* d_out, int out_size, void* d_ws, size_t ws_size,
                              hipStream_t stream) {
    const float* v    = (const float*)d_in[0];  // (32, 2000, 32)
    const float* adj  = (const float*)d_in[1];  // (32, 2000, 2000)
    const float* W1   = (const float*)d_in[2];  // (32, 32)
    const float* W2   = (const float*)d_in[3];  // (32, 32)
    const float* outw = (const float*)d_in[4];  // (10, 2000)
    const float* outb = (const float*)d_in[5];  // (10,)
    float* out = (float*)d_out;                 // (32, 10)

    char* ws = (char*)d_ws;
    float* bufA = (float*)(ws);                      // 8 MB slot: h1 then h2
    float* bufB = (float*)(ws + (8u << 20));         // 8 MB slot: y1
    float* bufS = (float*)(ws + (16u << 20));        // rowsums (32*2000 floats)

    const int rows = BB * NN;                        // 64000

    // K1: h1 = v @ W1
    {
        int tot = rows * FF;
        small_mm<<<dim3((tot + 255) / 256), dim3(256), 0, stream>>>(v, W1, bufA, rows);
    }
    // K2: y1 = relu(adj @ h1)
    {
        dim3 grid((NN + 255) / 256, BB);
        gcn_layer<false><<<grid, dim3(256), 0, stream>>>(adj, bufA, bufB, nullptr);
    }
    // K3: h2 = y1 @ W2
    {
        int tot = rows * FF;
        small_mm<<<dim3((tot + 255) / 256), dim3(256), 0, stream>>>(bufB, W2, bufA, rows);
    }
    // K4: s = sum_f relu(adj @ h2)
    {
        dim3 grid((NN + 255) / 256, BB);
        gcn_layer<true><<<grid, dim3(256), 0, stream>>>(adj, bufA, nullptr, bufS);
    }
    // K5: out = s @ out_w.T + out_b
    {
        dim3 grid(LL, BB);
        final_linear<<<grid, dim3(256), 0, stream>>>(bufS, outw, outb, out);
    }
}